// Round 1
// baseline (243.771 us; speedup 1.0000x reference)
//
#include <hip/hip_runtime.h>

#define CHUNKS 8

// Order-preserving float -> uint key (works for all finite floats):
// min over keys == min over floats.
__device__ __forceinline__ unsigned int f2key(float f) {
    unsigned int b = __float_as_uint(f);
    return (b & 0x80000000u) ? ~b : (b | 0x80000000u);
}
__device__ __forceinline__ float key2f(unsigned int k) {
    unsigned int b = (k & 0x80000000u) ? (k ^ 0x80000000u) : ~k;
    return __uint_as_float(b);
}

// Precompute stream-form points: (-2x, -2y, -2z, |p|^2), and init min arrays.
__global__ void chamfer_prep(const float* __restrict__ pred, const float* __restrict__ gt,
                             float4* __restrict__ predp, float4* __restrict__ gtp,
                             unsigned int* __restrict__ minF, unsigned int* __restrict__ minB,
                             int nP, int nG)
{
    int i = blockIdx.x * blockDim.x + threadIdx.x;
    if (i < nP) {
        float px = pred[3*i+0], py = pred[3*i+1], pz = pred[3*i+2];
        float p2 = fmaf(px, px, fmaf(py, py, pz*pz));
        predp[i] = make_float4(-2.f*px, -2.f*py, -2.f*pz, p2);
        minF[i] = 0xFFFFFFFFu;
    }
    if (i < nG) {
        float gx = gt[4*i+0], gy = gt[4*i+1], gz = gt[4*i+2];
        float g2 = fmaf(gx, gx, fmaf(gy, gy, gz*gz));
        gtp[i] = make_float4(-2.f*gx, -2.f*gy, -2.f*gz, g2);
        minB[i] = 0xFFFFFFFFu;
    }
}

// Each thread owns 2 points of the "own" set and streams a chunk of the
// opposite set, tracking min over e = |g|^2 - 2<p,g>  (p^2 added at finalize,
// clamp deferred: min(max(0,d2)) == max(0, min d2)).
__global__ __launch_bounds__(256) void chamfer_min(
    const float* __restrict__ pred, const float* __restrict__ gt,
    const float4* __restrict__ predp, const float4* __restrict__ gtp,
    unsigned int* __restrict__ minF, unsigned int* __restrict__ minB,
    int nP, int nG)
{
    const int dir = blockIdx.z;                 // 0: fwd (own pred, stream gt)
    const int nOwn = dir ? nG : nP;
    const int nStr = dir ? nP : nG;
    const float4* __restrict__ str = dir ? predp : gtp;
    unsigned int* mins = dir ? minB : minF;

    const int p0 = blockIdx.x * (2 * blockDim.x) + threadIdx.x;
    const int p1 = p0 + blockDim.x;
    const bool v0 = p0 < nOwn, v1 = p1 < nOwn;

    float4 P0 = make_float4(0.f, 0.f, 0.f, 0.f);
    float4 P1 = make_float4(0.f, 0.f, 0.f, 0.f);
    if (dir == 0) {
        if (v0) { P0.x = pred[3*p0+0]; P0.y = pred[3*p0+1]; P0.z = pred[3*p0+2]; }
        if (v1) { P1.x = pred[3*p1+0]; P1.y = pred[3*p1+1]; P1.z = pred[3*p1+2]; }
    } else {
        if (v0) { float4 g = ((const float4*)gt)[p0]; P0.x = g.x; P0.y = g.y; P0.z = g.z; }
        if (v1) { float4 g = ((const float4*)gt)[p1]; P1.x = g.x; P1.y = g.y; P1.z = g.z; }
    }

    const int csz = (nStr + CHUNKS - 1) / CHUNKS;
    const int c0 = blockIdx.y * csz;
    const int c1 = min(c0 + csz, nStr);

    float e0a = 3.0e38f, e0b = 3.0e38f, e1a = 3.0e38f, e1b = 3.0e38f;
    int m = c0;
    #pragma unroll 2
    for (; m + 1 < c1; m += 2) {
        float4 s0 = str[m];
        float4 s1 = str[m+1];
        float t0 = fmaf(s0.x, P0.x, fmaf(s0.y, P0.y, fmaf(s0.z, P0.z, s0.w)));
        float t1 = fmaf(s1.x, P0.x, fmaf(s1.y, P0.y, fmaf(s1.z, P0.z, s1.w)));
        float u0 = fmaf(s0.x, P1.x, fmaf(s0.y, P1.y, fmaf(s0.z, P1.z, s0.w)));
        float u1 = fmaf(s1.x, P1.x, fmaf(s1.y, P1.y, fmaf(s1.z, P1.z, s1.w)));
        e0a = fminf(e0a, t0); e0b = fminf(e0b, t1);
        e1a = fminf(e1a, u0); e1b = fminf(e1b, u1);
    }
    if (m < c1) {
        float4 s0 = str[m];
        e0a = fminf(e0a, fmaf(s0.x, P0.x, fmaf(s0.y, P0.y, fmaf(s0.z, P0.z, s0.w))));
        e1a = fminf(e1a, fmaf(s0.x, P1.x, fmaf(s0.y, P1.y, fmaf(s0.z, P1.z, s0.w))));
    }
    if (v0) atomicMin(&mins[p0], f2key(fminf(e0a, e0b)));
    if (v1) atomicMin(&mins[p1], f2key(fminf(e1a, e1b)));
}

// Single block: decode keys, add |p|^2, clamp, mean both directions, write scalar.
__global__ __launch_bounds__(1024) void chamfer_finalize(
    const unsigned int* __restrict__ minF, const unsigned int* __restrict__ minB,
    const float4* __restrict__ predp, const float4* __restrict__ gtp,
    float* __restrict__ out, int nP, int nG)
{
    float sF = 0.f, sB = 0.f;
    const int nmax = nP > nG ? nP : nG;
    for (int i = threadIdx.x; i < nmax; i += blockDim.x) {
        if (i < nP) sF += fmaxf(0.f, predp[i].w + key2f(minF[i]));
        if (i < nG) sB += fmaxf(0.f, gtp[i].w + key2f(minB[i]));
    }
    #pragma unroll
    for (int o = 32; o > 0; o >>= 1) { sF += __shfl_xor(sF, o); sB += __shfl_xor(sB, o); }
    __shared__ float rF[16], rB[16];
    const int wid = threadIdx.x >> 6, lane = threadIdx.x & 63;
    if (lane == 0) { rF[wid] = sF; rB[wid] = sB; }
    __syncthreads();
    if (threadIdx.x == 0) {
        float tF = 0.f, tB = 0.f;
        const int nw = (int)(blockDim.x >> 6);
        for (int w = 0; w < nw; ++w) { tF += rF[w]; tB += rB[w]; }
        out[0] = tF / (float)nP + tB / (float)nG;
    }
}

extern "C" void kernel_launch(void* const* d_in, const int* in_sizes, int n_in,
                              void* d_out, int out_size, void* d_ws, size_t ws_size,
                              hipStream_t stream)
{
    const float* pred = (const float*)d_in[0];
    const float* gt   = (const float*)d_in[1];
    const int nP = in_sizes[0] / 3;
    const int nG = in_sizes[1] / 4;

    char* ws = (char*)d_ws;
    size_t off = 0;
    auto take = [&](size_t bytes) -> void* {
        void* p = ws + off;
        off = (off + bytes + 255) & ~(size_t)255;
        return p;
    };
    float4* predp = (float4*)take((size_t)nP * 16);
    float4* gtp   = (float4*)take((size_t)nG * 16);
    unsigned int* minF = (unsigned int*)take((size_t)nP * 4);
    unsigned int* minB = (unsigned int*)take((size_t)nG * 4);
    (void)ws_size; (void)n_in; (void)out_size;

    const int nmax = nP > nG ? nP : nG;
    chamfer_prep<<<(nmax + 255) / 256, 256, 0, stream>>>(pred, gt, predp, gtp, minF, minB, nP, nG);

    const int blocksN = (nmax + 511) / 512;   // 2 points per thread, 256 threads
    dim3 grid(blocksN, CHUNKS, 2);
    chamfer_min<<<grid, 256, 0, stream>>>(pred, gt, predp, gtp, minF, minB, nP, nG);

    chamfer_finalize<<<1, 1024, 0, stream>>>(minF, minB, predp, gtp, (float*)d_out, nP, nG);
}

// Round 2
// 120.721 us; speedup vs baseline: 2.0193x; 2.0193x over previous
//
#include <hip/hip_runtime.h>

#define CHUNKS 48
#define ROWS 4           // own rows per thread
#define BLK 256

// Order-preserving float -> uint key: min over keys == min over floats.
__device__ __forceinline__ unsigned int f2key(float f) {
    unsigned int b = __float_as_uint(f);
    return (b & 0x80000000u) ? ~b : (b | 0x80000000u);
}
__device__ __forceinline__ float key2f(unsigned int k) {
    unsigned int b = (k & 0x80000000u) ? (k ^ 0x80000000u) : ~k;
    return __uint_as_float(b);
}

// Precompute stream-form points: (-2x, -2y, -2z, |p|^2), and init min arrays.
__global__ void chamfer_prep(const float* __restrict__ pred, const float* __restrict__ gt,
                             float4* __restrict__ predp, float4* __restrict__ gtp,
                             unsigned int* __restrict__ minF, unsigned int* __restrict__ minB,
                             int nP, int nG)
{
    int i = blockIdx.x * blockDim.x + threadIdx.x;
    if (i < nP) {
        float px = pred[3*i+0], py = pred[3*i+1], pz = pred[3*i+2];
        float p2 = fmaf(px, px, fmaf(py, py, pz*pz));
        predp[i] = make_float4(-2.f*px, -2.f*py, -2.f*pz, p2);
        minF[i] = 0xFFFFFFFFu;
    }
    if (i < nG) {
        float gx = gt[4*i+0], gy = gt[4*i+1], gz = gt[4*i+2];
        float g2 = fmaf(gx, gx, fmaf(gy, gy, gz*gz));
        gtp[i] = make_float4(-2.f*gx, -2.f*gy, -2.f*gz, g2);
        minB[i] = 0xFFFFFFFFu;
    }
}

// Each thread owns ROWS points; the wave streams a chunk of the opposite set
// via wave-uniform (scalar-cached) loads. Tracks min over e = |g|^2 - 2<p,g>;
// |p|^2 added at finalize (min/max commute with the deferred terms).
__global__ __launch_bounds__(BLK) void chamfer_min(
    const float* __restrict__ pred, const float* __restrict__ gt,
    const float4* __restrict__ predp, const float4* __restrict__ gtp,
    unsigned int* __restrict__ minF, unsigned int* __restrict__ minB,
    int nP, int nG)
{
    const int dir = blockIdx.z;                 // 0: own pred / stream gt
    const int nOwn = dir ? nG : nP;
    const int nStr = dir ? nP : nG;
    const float4* __restrict__ str = dir ? predp : gtp;
    unsigned int* mins = dir ? minB : minF;

    int   ridx[ROWS];
    float Px[ROWS], Py[ROWS], Pz[ROWS], e[ROWS];
    const int base = blockIdx.x * (ROWS * BLK) + threadIdx.x;
    #pragma unroll
    for (int k = 0; k < ROWS; ++k) {
        ridx[k] = base + k * BLK;
        int rc = ridx[k] < nOwn ? ridx[k] : (nOwn - 1);   // clamp: safe dummy work
        if (dir == 0) { Px[k] = pred[3*rc+0]; Py[k] = pred[3*rc+1]; Pz[k] = pred[3*rc+2]; }
        else          { float4 g = ((const float4*)gt)[rc]; Px[k] = g.x; Py[k] = g.y; Pz[k] = g.z; }
        e[k] = 3.0e38f;
    }

    const int csz = (nStr + CHUNKS - 1) / CHUNKS;
    const int c0 = blockIdx.y * csz;
    const int c1 = min(c0 + csz, nStr);

    int m = c0;
    for (; m + 3 < c1; m += 4) {
        float4 s0 = str[m], s1 = str[m+1], s2 = str[m+2], s3 = str[m+3];
        #pragma unroll
        for (int k = 0; k < ROWS; ++k) {
            float t0 = fmaf(s0.x, Px[k], fmaf(s0.y, Py[k], fmaf(s0.z, Pz[k], s0.w)));
            float t1 = fmaf(s1.x, Px[k], fmaf(s1.y, Py[k], fmaf(s1.z, Pz[k], s1.w)));
            float t2 = fmaf(s2.x, Px[k], fmaf(s2.y, Py[k], fmaf(s2.z, Pz[k], s2.w)));
            float t3 = fmaf(s3.x, Px[k], fmaf(s3.y, Py[k], fmaf(s3.z, Pz[k], s3.w)));
            float x = fminf(fminf(t0, t1), t2);           // -> v_min3_f32
            e[k] = fminf(fminf(x, t3), e[k]);             // -> v_min3_f32
        }
    }
    for (; m < c1; ++m) {
        float4 s0 = str[m];
        #pragma unroll
        for (int k = 0; k < ROWS; ++k) {
            float t0 = fmaf(s0.x, Px[k], fmaf(s0.y, Py[k], fmaf(s0.z, Pz[k], s0.w)));
            e[k] = fminf(e[k], t0);
        }
    }

    #pragma unroll
    for (int k = 0; k < ROWS; ++k)
        if (ridx[k] < nOwn) atomicMin(&mins[ridx[k]], f2key(e[k]));
}

// Single block: decode keys, add |p|^2, clamp, mean both directions.
__global__ __launch_bounds__(1024) void chamfer_finalize(
    const unsigned int* __restrict__ minF, const unsigned int* __restrict__ minB,
    const float4* __restrict__ predp, const float4* __restrict__ gtp,
    float* __restrict__ out, int nP, int nG)
{
    float sF = 0.f, sB = 0.f;
    const int nmax = nP > nG ? nP : nG;
    for (int i = threadIdx.x; i < nmax; i += blockDim.x) {
        if (i < nP) sF += fmaxf(0.f, predp[i].w + key2f(minF[i]));
        if (i < nG) sB += fmaxf(0.f, gtp[i].w + key2f(minB[i]));
    }
    #pragma unroll
    for (int o = 32; o > 0; o >>= 1) { sF += __shfl_xor(sF, o); sB += __shfl_xor(sB, o); }
    __shared__ float rF[16], rB[16];
    const int wid = threadIdx.x >> 6, lane = threadIdx.x & 63;
    if (lane == 0) { rF[wid] = sF; rB[wid] = sB; }
    __syncthreads();
    if (threadIdx.x == 0) {
        float tF = 0.f, tB = 0.f;
        const int nw = (int)(blockDim.x >> 6);
        for (int w = 0; w < nw; ++w) { tF += rF[w]; tB += rB[w]; }
        out[0] = tF / (float)nP + tB / (float)nG;
    }
}

extern "C" void kernel_launch(void* const* d_in, const int* in_sizes, int n_in,
                              void* d_out, int out_size, void* d_ws, size_t ws_size,
                              hipStream_t stream)
{
    const float* pred = (const float*)d_in[0];
    const float* gt   = (const float*)d_in[1];
    const int nP = in_sizes[0] / 3;
    const int nG = in_sizes[1] / 4;

    char* ws = (char*)d_ws;
    size_t off = 0;
    auto take = [&](size_t bytes) -> void* {
        void* p = ws + off;
        off = (off + bytes + 255) & ~(size_t)255;
        return p;
    };
    float4* predp = (float4*)take((size_t)nP * 16);
    float4* gtp   = (float4*)take((size_t)nG * 16);
    unsigned int* minF = (unsigned int*)take((size_t)nP * 4);
    unsigned int* minB = (unsigned int*)take((size_t)nG * 4);
    (void)ws_size; (void)n_in; (void)out_size;

    const int nmax = nP > nG ? nP : nG;
    chamfer_prep<<<(nmax + 255) / 256, 256, 0, stream>>>(pred, gt, predp, gtp, minF, minB, nP, nG);

    const int rowBlocks = (nmax + ROWS * BLK - 1) / (ROWS * BLK);
    dim3 grid(rowBlocks, CHUNKS, 2);
    chamfer_min<<<grid, BLK, 0, stream>>>(pred, gt, predp, gtp, minF, minB, nP, nG);

    chamfer_finalize<<<1, 1024, 0, stream>>>(minF, minB, predp, gtp, (float*)d_out, nP, nG);
}

// Round 3
// 89.820 us; speedup vs baseline: 2.7140x; 1.3440x over previous
//
#include <hip/hip_runtime.h>

typedef float v2f __attribute__((ext_vector_type(2)));

#define BLK   256
#define ROWS  8                    // own points per thread
#define OWN_PER_BLK (ROWS * BLK)   // 2048
#define CHUNK 256                  // stream points per y-block (== BLK, multiple of 4)

static_assert(CHUNK == BLK, "staging assumes one point per thread");

__device__ __forceinline__ v2f pk_fma(v2f a, v2f b, v2f c) {
    v2f d;
    asm("v_pk_fma_f32 %0, %1, %2, %3" : "=v"(d) : "v"(a), "v"(b), "v"(c));
    return d;
}
__device__ __forceinline__ float min3f(float a, float b, float c) {
    float d;
    asm("v_min3_f32 %0, %1, %2, %3" : "=v"(d) : "v"(a), "v"(b), "v"(c));
    return d;
}

// Order-preserving float -> uint key: min over keys == min over floats.
__device__ __forceinline__ unsigned int f2key(float f) {
    unsigned int b = __float_as_uint(f);
    return (b & 0x80000000u) ? ~b : (b | 0x80000000u);
}
__device__ __forceinline__ float key2f(unsigned int k) {
    unsigned int b = (k & 0x80000000u) ? (k ^ 0x80000000u) : ~k;
    return __uint_as_float(b);
}

// Precompute stream-form points: (x, y, z, |p|^2) with a -2 folded at use
// site? No: keep (-2x,-2y,-2z,|p|^2) so inner fma is s.x*P + ... + s.w.
__global__ void chamfer_prep(const float* __restrict__ pred, const float* __restrict__ gt,
                             float4* __restrict__ predp, float4* __restrict__ gtp,
                             unsigned int* __restrict__ minF, unsigned int* __restrict__ minB,
                             int nP, int nG)
{
    int i = blockIdx.x * blockDim.x + threadIdx.x;
    if (i < nP) {
        float px = pred[3*i+0], py = pred[3*i+1], pz = pred[3*i+2];
        float p2 = fmaf(px, px, fmaf(py, py, pz*pz));
        predp[i] = make_float4(-2.f*px, -2.f*py, -2.f*pz, p2);
        minF[i] = 0xFFFFFFFFu;
    }
    if (i < nG) {
        float gx = gt[4*i+0], gy = gt[4*i+1], gz = gt[4*i+2];
        float g2 = fmaf(gx, gx, fmaf(gy, gy, gz*gz));
        gtp[i] = make_float4(-2.f*gx, -2.f*gy, -2.f*gz, g2);
        minB[i] = 0xFFFFFFFFu;
    }
}

// Each thread owns ROWS points; block stages a CHUNK of the opposite set into
// LDS (quad-SoA: x0..x3|y0..y3|z0..z3|w0..w3 per quad) and streams it with
// uniform-address ds_reads (HW broadcast). Inner math: v_pk_fma_f32 pairs +
// v_min3_f32 accumulate = 2 VALU instrs per pair. Tracks min over
// e = |g|^2 - 2<p,g>; |p|^2 added at finalize.
__global__ __launch_bounds__(BLK) void chamfer_min(
    const float* __restrict__ pred, const float* __restrict__ gt,
    const float4* __restrict__ predp, const float4* __restrict__ gtp,
    unsigned int* __restrict__ minF, unsigned int* __restrict__ minB,
    int nP, int nG)
{
    __shared__ float sh[CHUNK * 4];

    const int dir = blockIdx.z;                 // 0: own pred / stream gt
    const int nOwn = dir ? nG : nP;
    const int nStr = dir ? nP : nG;
    const float4* __restrict__ str = dir ? predp : gtp;
    unsigned int* mins = dir ? minB : minF;

    // --- stage chunk into LDS (pad with w=3e38 so pads never win the min) ---
    {
        const int j = threadIdx.x;
        const int g = blockIdx.y * CHUNK + j;
        float4 f = (g < nStr) ? str[g] : make_float4(0.f, 0.f, 0.f, 3.0e38f);
        const int q = j >> 2, r = j & 3;
        sh[q*16 + r + 0]  = f.x;
        sh[q*16 + r + 4]  = f.y;
        sh[q*16 + r + 8]  = f.z;
        sh[q*16 + r + 12] = f.w;
    }

    // --- own rows: P duplicated into both packed halves ---
    int ridx[ROWS];
    v2f Pxx[ROWS], Pyy[ROWS], Pzz[ROWS];
    float e[ROWS];
    const int base = blockIdx.x * OWN_PER_BLK + threadIdx.x;
    #pragma unroll
    for (int k = 0; k < ROWS; ++k) {
        ridx[k] = base + k * BLK;
        const int rc = ridx[k] < nOwn ? ridx[k] : (nOwn - 1);   // clamp: dummy work
        float px, py, pz;
        if (dir == 0) { px = pred[3*rc+0]; py = pred[3*rc+1]; pz = pred[3*rc+2]; }
        else          { float4 g4 = ((const float4*)gt)[rc]; px = g4.x; py = g4.y; pz = g4.z; }
        Pxx[k] = v2f{px, px}; Pyy[k] = v2f{py, py}; Pzz[k] = v2f{pz, pz};
        e[k] = 3.0e38f;
    }
    __syncthreads();

    // --- hot loop: per quad, 8 uniform ds_reads + ROWS*(6 pk_fma + 2 min3) ---
    const int nQ = CHUNK / 4;
    #pragma unroll 2
    for (int q = 0; q < nQ; ++q) {
        const float* s = &sh[q * 16];
        const v2f X01 = *(const v2f*)(s + 0),  X23 = *(const v2f*)(s + 2);
        const v2f Y01 = *(const v2f*)(s + 4),  Y23 = *(const v2f*)(s + 6);
        const v2f Z01 = *(const v2f*)(s + 8),  Z23 = *(const v2f*)(s + 10);
        const v2f W01 = *(const v2f*)(s + 12), W23 = *(const v2f*)(s + 14);
        #pragma unroll
        for (int k = 0; k < ROWS; ++k) {
            v2f a = pk_fma(X01, Pxx[k], pk_fma(Y01, Pyy[k], pk_fma(Z01, Pzz[k], W01)));
            v2f b = pk_fma(X23, Pxx[k], pk_fma(Y23, Pyy[k], pk_fma(Z23, Pzz[k], W23)));
            e[k] = min3f(e[k], a.x, a.y);
            e[k] = min3f(e[k], b.x, b.y);
        }
    }

    #pragma unroll
    for (int k = 0; k < ROWS; ++k)
        if (ridx[k] < nOwn) atomicMin(&mins[ridx[k]], f2key(e[k]));
}

// Single block: decode keys, add |p|^2, clamp, mean both directions.
__global__ __launch_bounds__(1024) void chamfer_finalize(
    const unsigned int* __restrict__ minF, const unsigned int* __restrict__ minB,
    const float4* __restrict__ predp, const float4* __restrict__ gtp,
    float* __restrict__ out, int nP, int nG)
{
    float sF = 0.f, sB = 0.f;
    const int nmax = nP > nG ? nP : nG;
    for (int i = threadIdx.x; i < nmax; i += blockDim.x) {
        if (i < nP) sF += fmaxf(0.f, predp[i].w + key2f(minF[i]));
        if (i < nG) sB += fmaxf(0.f, gtp[i].w + key2f(minB[i]));
    }
    #pragma unroll
    for (int o = 32; o > 0; o >>= 1) { sF += __shfl_xor(sF, o); sB += __shfl_xor(sB, o); }
    __shared__ float rF[16], rB[16];
    const int wid = threadIdx.x >> 6, lane = threadIdx.x & 63;
    if (lane == 0) { rF[wid] = sF; rB[wid] = sB; }
    __syncthreads();
    if (threadIdx.x == 0) {
        float tF = 0.f, tB = 0.f;
        const int nw = (int)(blockDim.x >> 6);
        for (int w = 0; w < nw; ++w) { tF += rF[w]; tB += rB[w]; }
        out[0] = tF / (float)nP + tB / (float)nG;
    }
}

extern "C" void kernel_launch(void* const* d_in, const int* in_sizes, int n_in,
                              void* d_out, int out_size, void* d_ws, size_t ws_size,
                              hipStream_t stream)
{
    const float* pred = (const float*)d_in[0];
    const float* gt   = (const float*)d_in[1];
    const int nP = in_sizes[0] / 3;
    const int nG = in_sizes[1] / 4;

    char* ws = (char*)d_ws;
    size_t off = 0;
    auto take = [&](size_t bytes) -> void* {
        void* p = ws + off;
        off = (off + bytes + 255) & ~(size_t)255;
        return p;
    };
    float4* predp = (float4*)take((size_t)nP * 16);
    float4* gtp   = (float4*)take((size_t)nG * 16);
    unsigned int* minF = (unsigned int*)take((size_t)nP * 4);
    unsigned int* minB = (unsigned int*)take((size_t)nG * 4);
    (void)ws_size; (void)n_in; (void)out_size;

    const int nmax = nP > nG ? nP : nG;
    chamfer_prep<<<(nmax + 255) / 256, 256, 0, stream>>>(pred, gt, predp, gtp, minF, minB, nP, nG);

    const int xB = (nmax + OWN_PER_BLK - 1) / OWN_PER_BLK;   // 10
    const int yB = (nmax + CHUNK - 1) / CHUNK;               // 79
    dim3 grid(xB, yB, 2);
    chamfer_min<<<grid, BLK, 0, stream>>>(pred, gt, predp, gtp, minF, minB, nP, nG);

    chamfer_finalize<<<1, 1024, 0, stream>>>(minF, minB, predp, gtp, (float*)d_out, nP, nG);
}

// Round 4
// 88.164 us; speedup vs baseline: 2.7650x; 1.0188x over previous
//
#include <hip/hip_runtime.h>

#define BLK   256
#define ROWS  8                    // own points per thread
#define OWN_PER_BLK (ROWS * BLK)   // 2048
#define CHUNK 256                  // stream points per y-block (== BLK)

static_assert(CHUNK == BLK, "staging assumes one point per thread");

__device__ __forceinline__ float min3f(float a, float b, float c) {
    float d;
    asm("v_min3_f32 %0, %1, %2, %3" : "=v"(d) : "v"(a), "v"(b), "v"(c));
    return d;
}

// Order-preserving float -> uint key: min over keys == min over floats.
__device__ __forceinline__ unsigned int f2key(float f) {
    unsigned int b = __float_as_uint(f);
    return (b & 0x80000000u) ? ~b : (b | 0x80000000u);
}
__device__ __forceinline__ float key2f(unsigned int k) {
    unsigned int b = (k & 0x80000000u) ? (k ^ 0x80000000u) : ~k;
    return __uint_as_float(b);
}

// Precompute stream-form points: (-2x, -2y, -2z, |p|^2); init min arrays.
__global__ void chamfer_prep(const float* __restrict__ pred, const float* __restrict__ gt,
                             float4* __restrict__ predp, float4* __restrict__ gtp,
                             unsigned int* __restrict__ minF, unsigned int* __restrict__ minB,
                             int nP, int nG)
{
    int i = blockIdx.x * blockDim.x + threadIdx.x;
    if (i < nP) {
        float px = pred[3*i+0], py = pred[3*i+1], pz = pred[3*i+2];
        float p2 = fmaf(px, px, fmaf(py, py, pz*pz));
        predp[i] = make_float4(-2.f*px, -2.f*py, -2.f*pz, p2);
        minF[i] = 0xFFFFFFFFu;
    }
    if (i < nG) {
        float gx = gt[4*i+0], gy = gt[4*i+1], gz = gt[4*i+2];
        float g2 = fmaf(gx, gx, fmaf(gy, gy, gz*gz));
        gtp[i] = make_float4(-2.f*gx, -2.f*gy, -2.f*gz, g2);
        minB[i] = 0xFFFFFFFFu;
    }
}

// Each thread owns ROWS points (scalar P: 3 VGPR/row); block stages a CHUNK of
// the opposite set into LDS as AoS float4 (one conflict-free ds_write_b128 per
// thread) and streams it with uniform-address ds_read_b128 (HW broadcast).
// Scalar fp32 fma is full-rate on gfx950 (pk_fma is half-rate: no win, 2x regs).
// Tracks min over e = |g|^2 - 2<p,g>; |p|^2 added at finalize.
__global__ __launch_bounds__(BLK, 7) void chamfer_min(
    const float* __restrict__ pred, const float* __restrict__ gt,
    const float4* __restrict__ predp, const float4* __restrict__ gtp,
    unsigned int* __restrict__ minF, unsigned int* __restrict__ minB,
    int nP, int nG)
{
    __shared__ float4 sh[CHUNK];

    const int dir = blockIdx.z;                 // 0: own pred / stream gt
    const int nOwn = dir ? nG : nP;
    const int nStr = dir ? nP : nG;
    const float4* __restrict__ str = dir ? predp : gtp;
    unsigned int* mins = dir ? minB : minF;

    // --- stage chunk into LDS (pad with w=3e38 so pads never win the min) ---
    {
        const int j = threadIdx.x;
        const int g = blockIdx.y * CHUNK + j;
        sh[j] = (g < nStr) ? str[g] : make_float4(0.f, 0.f, 0.f, 3.0e38f);
    }

    // --- own rows (scalar registers) ---
    float Px[ROWS], Py[ROWS], Pz[ROWS], e[ROWS];
    const int base = blockIdx.x * OWN_PER_BLK + threadIdx.x;
    #pragma unroll
    for (int k = 0; k < ROWS; ++k) {
        const int r = base + k * BLK;
        const int rc = r < nOwn ? r : (nOwn - 1);   // clamp: harmless dummy work
        if (dir == 0) { Px[k] = pred[3*rc+0]; Py[k] = pred[3*rc+1]; Pz[k] = pred[3*rc+2]; }
        else          { float4 g4 = ((const float4*)gt)[rc]; Px[k] = g4.x; Py[k] = g4.y; Pz[k] = g4.z; }
        e[k] = 3.0e38f;
    }
    __syncthreads();

    // --- hot loop: 4 uniform ds_read_b128 + ROWS*(12 fma + 2 min3) per quad ---
    #pragma unroll 2
    for (int q = 0; q < CHUNK / 4; ++q) {
        const float4 s0 = sh[q*4+0], s1 = sh[q*4+1], s2 = sh[q*4+2], s3 = sh[q*4+3];
        #pragma unroll
        for (int k = 0; k < ROWS; ++k) {
            float t0 = fmaf(s0.x, Px[k], fmaf(s0.y, Py[k], fmaf(s0.z, Pz[k], s0.w)));
            float t1 = fmaf(s1.x, Px[k], fmaf(s1.y, Py[k], fmaf(s1.z, Pz[k], s1.w)));
            float t2 = fmaf(s2.x, Px[k], fmaf(s2.y, Py[k], fmaf(s2.z, Pz[k], s2.w)));
            float t3 = fmaf(s3.x, Px[k], fmaf(s3.y, Py[k], fmaf(s3.z, Pz[k], s3.w)));
            e[k] = min3f(e[k], t0, t1);
            e[k] = min3f(e[k], t2, t3);
        }
    }

    #pragma unroll
    for (int k = 0; k < ROWS; ++k) {
        const int r = base + k * BLK;
        if (r < nOwn) atomicMin(&mins[r], f2key(e[k]));
    }
}

// Single block: decode keys, add |p|^2, clamp, mean both directions.
__global__ __launch_bounds__(1024) void chamfer_finalize(
    const unsigned int* __restrict__ minF, const unsigned int* __restrict__ minB,
    const float4* __restrict__ predp, const float4* __restrict__ gtp,
    float* __restrict__ out, int nP, int nG)
{
    float sF = 0.f, sB = 0.f;
    const int nmax = nP > nG ? nP : nG;
    for (int i = threadIdx.x; i < nmax; i += blockDim.x) {
        if (i < nP) sF += fmaxf(0.f, predp[i].w + key2f(minF[i]));
        if (i < nG) sB += fmaxf(0.f, gtp[i].w + key2f(minB[i]));
    }
    #pragma unroll
    for (int o = 32; o > 0; o >>= 1) { sF += __shfl_xor(sF, o); sB += __shfl_xor(sB, o); }
    __shared__ float rF[16], rB[16];
    const int wid = threadIdx.x >> 6, lane = threadIdx.x & 63;
    if (lane == 0) { rF[wid] = sF; rB[wid] = sB; }
    __syncthreads();
    if (threadIdx.x == 0) {
        float tF = 0.f, tB = 0.f;
        const int nw = (int)(blockDim.x >> 6);
        for (int w = 0; w < nw; ++w) { tF += rF[w]; tB += rB[w]; }
        out[0] = tF / (float)nP + tB / (float)nG;
    }
}

extern "C" void kernel_launch(void* const* d_in, const int* in_sizes, int n_in,
                              void* d_out, int out_size, void* d_ws, size_t ws_size,
                              hipStream_t stream)
{
    const float* pred = (const float*)d_in[0];
    const float* gt   = (const float*)d_in[1];
    const int nP = in_sizes[0] / 3;
    const int nG = in_sizes[1] / 4;

    char* ws = (char*)d_ws;
    size_t off = 0;
    auto take = [&](size_t bytes) -> void* {
        void* p = ws + off;
        off = (off + bytes + 255) & ~(size_t)255;
        return p;
    };
    float4* predp = (float4*)take((size_t)nP * 16);
    float4* gtp   = (float4*)take((size_t)nG * 16);
    unsigned int* minF = (unsigned int*)take((size_t)nP * 4);
    unsigned int* minB = (unsigned int*)take((size_t)nG * 4);
    (void)ws_size; (void)n_in; (void)out_size;

    const int nmax = nP > nG ? nP : nG;
    chamfer_prep<<<(nmax + 255) / 256, 256, 0, stream>>>(pred, gt, predp, gtp, minF, minB, nP, nG);

    const int xB = (nmax + OWN_PER_BLK - 1) / OWN_PER_BLK;   // 10
    const int yB = (nmax + CHUNK - 1) / CHUNK;               // 79
    dim3 grid(xB, yB, 2);
    chamfer_min<<<grid, BLK, 0, stream>>>(pred, gt, predp, gtp, minF, minB, nP, nG);

    chamfer_finalize<<<1, 1024, 0, stream>>>(minF, minB, predp, gtp, (float*)d_out, nP, nG);
}